// Round 5
// baseline (67.326 us; speedup 1.0000x reference)
//
#include <hip/hip_runtime.h>

#define BLOCK 256

// One thread per atom. Wave-private LDS out-staging, b128-aligned rows
// (32 floats) with XOR swizzle -> 7 ds_write_b128 + 7 ds_read_b128 per
// thread/tile, conflict-free. No block barriers, no sched_barrier fences
// (compiler free to pipeline across tiles); intra-wave RAW ordered by
// s_waitcnt lgkmcnt(0) + memory clobber.
__global__ __launch_bounds__(BLOCK, 4) void efp_kernel(
    const float* __restrict__ info,   // [M,7]
    const float* __restrict__ mask,   // [M]
    const float* __restrict__ W,      // [16,5]  (uniform -> SGPR)
    const float* __restrict__ bias,   // [16]
    const float* __restrict__ atom,   // [95,8]
    const float* __restrict__ typ,    // [6,4]
    float* __restrict__ out,          // [M,28]
    int ntiles)
{
    __shared__ float4 s_atom[95 * 3];        // rows padded to 48B
    __shared__ float4 s_typ[6];
    __shared__ float4 s_out4[4][64 * 8];     // per-wave; row = 8 float4 (128B)

    const int tid = threadIdx.x;
    const int wid = tid >> 6;
    const int lane = tid & 63;

    if (tid < 190) {
        const int a = tid >> 1, j = tid & 1;
        s_atom[a * 3 + j] = reinterpret_cast<const float4*>(atom)[tid];
    }
    if (tid < 6) s_typ[tid] = reinterpret_cast<const float4*>(typ)[tid];
    __syncthreads();                         // only block barrier

    float4* const sw4 = s_out4[wid];

    for (int tile = blockIdx.x; tile < ntiles; tile += gridDim.x) {
        const long long abase = (long long)tile * BLOCK + wid * 64;
        const long long i = abase + lane;

        const float m = mask[i];
        const float* gi = info + i * 7;
        const float r0 = gi[0], r1 = gi[1], r2 = gi[2], r3 = gi[3],
                    r4 = gi[4], r5 = gi[5], r6 = gi[6];

        // exact reference semantics
        const float f0 = r0 * m, f1 = r1 * m, f2 = r2 * m, f3 = r3 * m, f4 = r4 * m;
        const int an = (int)(r5 * m);        // trunc toward zero (.astype int32)
        const int et = (int)(r6 * m);
        const bool active = (m >= 0.5f);
        const bool valid  = active && (an >= 1) && (an <= 94);
        const int anc = min(max(an, 0), 94);
        const int etc = min(max(et, 0), 5);
        const float sc_ff  = active ? m : 0.0f;   // folds where(active)·mask
        const float sc_emb = valid  ? m : 0.0f;

        float4 o[7];
        float* of = reinterpret_cast<float*>(o);
        #pragma unroll
        for (int oo = 0; oo < 16; ++oo) {
            float acc = bias[oo];
            acc = fmaf(W[oo * 5 + 0], f0, acc);
            acc = fmaf(W[oo * 5 + 1], f1, acc);
            acc = fmaf(W[oo * 5 + 2], f2, acc);
            acc = fmaf(W[oo * 5 + 3], f3, acc);
            acc = fmaf(W[oo * 5 + 4], f4, acc);
            of[oo] = fmaxf(acc, 0.0f) * sc_ff;
        }
        const float4 a0 = s_atom[anc * 3 + 0];
        const float4 a1 = s_atom[anc * 3 + 1];
        const float4 t0 = s_typ[etc];
        o[4] = make_float4(a0.x * sc_emb, a0.y * sc_emb, a0.z * sc_emb, a0.w * sc_emb);
        o[5] = make_float4(a1.x * sc_emb, a1.y * sc_emb, a1.z * sc_emb, a1.w * sc_emb);
        o[6] = make_float4(t0.x * sc_emb, t0.y * sc_emb, t0.z * sc_emb, t0.w * sc_emb);

        // wave-private transpose: write own row (swizzled b128 slots)
        #pragma unroll
        for (int q = 0; q < 7; ++q)
            sw4[(lane * 8 + q) ^ (lane & 7)] = o[q];

        // cross-lane RAW: writes complete before reads (HW in-order per wave;
        // clobber stops compiler reordering the DS ops)
        asm volatile("s_waitcnt lgkmcnt(0)" ::: "memory");

        // coop store: 448 contiguous float4 (7168B) for this wave's 64 atoms
        float4* go = reinterpret_cast<float4*>(out) + abase * 7;
        #pragma unroll
        for (int k = 0; k < 7; ++k) {
            const int l = k * 64 + lane;           // 0..447
            const int row = l / 7;                 // magic-mul
            const int c = l - row * 7;
            go[l] = sw4[(row * 8 + c) ^ (row & 7)];
        }

        // WAR across iterations: compiler-side ordering only (HW is in-order)
        asm volatile("" ::: "memory");
    }
}

extern "C" void kernel_launch(void* const* d_in, const int* in_sizes, int n_in,
                              void* d_out, int out_size, void* d_ws, size_t ws_size,
                              hipStream_t stream) {
    const float* info = (const float*)d_in[0];
    const float* mask = (const float*)d_in[1];
    const float* W    = (const float*)d_in[2];
    const float* bias = (const float*)d_in[3];
    const float* atom = (const float*)d_in[4];
    const float* typ  = (const float*)d_in[5];
    float* out = (float*)d_out;

    const int M = in_sizes[1];           // B*N, divisible by 256
    const int ntiles = M / BLOCK;        // 8192
    int grid = ntiles < 1024 ? ntiles : 1024;   // match 4 blocks/CU residency

    hipLaunchKernelGGL(efp_kernel, dim3(grid), dim3(BLOCK), 0, stream,
                       info, mask, W, bias, atom, typ, out, ntiles);
}

// Round 7
// 60.221 us; speedup vs baseline: 1.1180x; 1.1180x over previous
//
#include <hip/hip_runtime.h>

#define BLOCK 256

typedef float f32x4 __attribute__((ext_vector_type(4)));  // clang vector type: valid for NT builtins

// One thread per atom, wave-private staging, no block barriers in loop.
// Input: wave coop-loads its 64 atoms' info (112 float4, contiguous, NT)
// into the SAME LDS region later used for output staging, re-reads per-atom
// as 7x ds_read_b32 (7 coprime 32 -> conflict-free). Output: per-lane
// ds_write_b128 x7 at stride 7 (mod-8 spread), coop float4 NT stores
// (1024B/instr). DS pipe is in-order per wave; section ordering enforced
// with memory clobbers (pattern HW-validated in rounds 3-5).
__global__ __launch_bounds__(BLOCK, 4) void efp_kernel(
    const float* __restrict__ info,   // [M,7]
    const float* __restrict__ mask,   // [M]
    const float* __restrict__ W,      // [16,5]  (uniform -> SGPR)
    const float* __restrict__ bias,   // [16]
    const float* __restrict__ atom,   // [95,8]
    const float* __restrict__ typ,    // [6,4]
    float* __restrict__ out,          // [M,28]
    int ntiles)
{
    __shared__ f32x4 s_atom[95 * 3];       // rows padded to 48B -> 8 bank groups
    __shared__ f32x4 s_typ[6];
    __shared__ f32x4 s_stage[4][64 * 7];   // per-wave: in-stage (112) / out-stage (448)

    const int tid = threadIdx.x;
    const int wid = tid >> 6;
    const int lane = tid & 63;

    if (tid < 190) {
        const int a = tid >> 1, j = tid & 1;
        s_atom[a * 3 + j] = reinterpret_cast<const f32x4*>(atom)[tid];
    }
    if (tid < 6) s_typ[tid] = reinterpret_cast<const f32x4*>(typ)[tid];
    __syncthreads();                       // only block barrier

    f32x4* const sw4 = s_stage[wid];
    const float* const swf = reinterpret_cast<const float*>(sw4);

    for (int tile = blockIdx.x; tile < ntiles; tile += gridDim.x) {
        const long long abase = (long long)tile * BLOCK + wid * 64;  // wave's atoms
        const long long i = abase + lane;

        // ---- coop input stage: 112 contiguous float4 (1792B), NT ----
        const f32x4* src4 = reinterpret_cast<const f32x4*>(info + abase * 7);
        sw4[lane] = __builtin_nontemporal_load(src4 + lane);
        if (lane < 48)
            sw4[64 + lane] = __builtin_nontemporal_load(src4 + 64 + lane);
        const float m = __builtin_nontemporal_load(mask + i);

        asm volatile("s_waitcnt lgkmcnt(0)" ::: "memory");  // in-stage visible

        // ---- per-atom input read: float idx 7*lane+k, banks (7l+k)%32 distinct
        float r[7];
        #pragma unroll
        for (int k = 0; k < 7; ++k) r[k] = swf[lane * 7 + k];

        // ---- exact reference semantics ----
        const float f0 = r[0] * m, f1 = r[1] * m, f2 = r[2] * m,
                    f3 = r[3] * m, f4 = r[4] * m;
        const int an = (int)(r[5] * m);        // trunc toward zero (.astype int32)
        const int et = (int)(r[6] * m);
        const bool active = (m >= 0.5f);
        const bool valid  = active && (an >= 1) && (an <= 94);
        const int anc = min(max(an, 0), 94);
        const int etc = min(max(et, 0), 5);
        const float sc_ff  = active ? m : 0.0f;  // folds where(active)·mask
        const float sc_emb = valid  ? m : 0.0f;

        f32x4 o[7];
        float* of = reinterpret_cast<float*>(o);
        #pragma unroll
        for (int oo = 0; oo < 16; ++oo) {
            float acc = bias[oo];
            acc = fmaf(W[oo * 5 + 0], f0, acc);
            acc = fmaf(W[oo * 5 + 1], f1, acc);
            acc = fmaf(W[oo * 5 + 2], f2, acc);
            acc = fmaf(W[oo * 5 + 3], f3, acc);
            acc = fmaf(W[oo * 5 + 4], f4, acc);
            of[oo] = fmaxf(acc, 0.0f) * sc_ff;
        }
        const f32x4 a0 = s_atom[anc * 3 + 0];
        const f32x4 a1 = s_atom[anc * 3 + 1];
        const f32x4 t0 = s_typ[etc];
        o[4] = a0 * sc_emb;
        o[5] = a1 * sc_emb;
        o[6] = t0 * sc_emb;

        // ALL input ds_reads must issue before out-stage ds_writes (region
        // aliased; DS pipe in-order per wave; clobber pins compiler order)
        asm volatile("" ::: "memory");

        // ---- out-stage: slot 7*lane+q, (7l+q)%8 bank-group spread ----
        #pragma unroll
        for (int q = 0; q < 7; ++q)
            sw4[lane * 7 + q] = o[q];

        asm volatile("s_waitcnt lgkmcnt(0)" ::: "memory");  // out-stage visible

        // ---- coop NT store: 448 contiguous float4 (7168B), linear LDS reads
        f32x4* go = reinterpret_cast<f32x4*>(out) + abase * 7;
        #pragma unroll
        for (int k = 0; k < 7; ++k) {
            const int l = k * 64 + lane;
            __builtin_nontemporal_store(sw4[l], go + l);
        }

        // WAR vs next tile's in-stage writes (pipe in-order; compiler barrier)
        asm volatile("" ::: "memory");
    }
}

extern "C" void kernel_launch(void* const* d_in, const int* in_sizes, int n_in,
                              void* d_out, int out_size, void* d_ws, size_t ws_size,
                              hipStream_t stream) {
    const float* info = (const float*)d_in[0];
    const float* mask = (const float*)d_in[1];
    const float* W    = (const float*)d_in[2];
    const float* bias = (const float*)d_in[3];
    const float* atom = (const float*)d_in[4];
    const float* typ  = (const float*)d_in[5];
    float* out = (float*)d_out;

    const int M = in_sizes[1];           // B*N, divisible by 256
    const int ntiles = M / BLOCK;        // 8192
    int grid = ntiles < 2048 ? ntiles : 2048;

    hipLaunchKernelGGL(efp_kernel, dim3(grid), dim3(BLOCK), 0, stream,
                       info, mask, W, bias, atom, typ, out, ntiles);
}